// Round 3
// baseline (272.840 us; speedup 1.0000x reference)
//
#include <hip/hip_runtime.h>

// out[b,s,i*64+j] = max(x[b,s,i], kernel[i,j])
// B=8, S=2048, I=64, O=64. Output = 67,108,864 fp32 = 256 MiB. Pure write-bound.
//
// float4 index v: row = v>>10, rem = v&1023, i = rem>>4, kernel float4 = rem.
// Grid-stride is a multiple of 1024 float4s => rem (and hence i and the
// kernel fragment) is LOOP-INVARIANT per thread: hoist the kernel-matrix
// load out of the loop entirely (no LDS, no syncthreads, no per-iter read).
// Per iteration: 1 broadcast x-load (16 lanes/address, L1/L2-hot),
// 4 v_max_f32, 1 non-temporal global_store_dwordx4 (don't thrash L2 with
// the 256 MiB output stream).
//
// NOTE: __builtin_nontemporal_store needs a clang ext-vector type, not
// HIP's float4 class — use v4f below.

typedef float v4f __attribute__((ext_vector_type(4)));

__global__ __launch_bounds__(256) void fuzzy_max_kernel(
    const float* __restrict__ x,
    const float* __restrict__ km,
    float* __restrict__ out,
    unsigned total4) {
  const unsigned v0 = blockIdx.x * blockDim.x + threadIdx.x;
  const unsigned rem = v0 & 1023u;   // invariant: position within 4096-wide row
  const unsigned i = rem >> 4;       // invariant: input-feature index

  // One 16 B load from the 16 KiB kernel table (L1/L2 resident) per thread.
  const v4f k = reinterpret_cast<const v4f*>(km)[rem];

  const unsigned stride = gridDim.x * blockDim.x;      // multiple of 1024
  const unsigned rowstep = stride >> 10;               // rows per iteration
  unsigned row = v0 >> 10;

  v4f* out4 = reinterpret_cast<v4f*>(out);
  for (unsigned v = v0; v < total4; v += stride, row += rowstep) {
    const float xv = x[(row << 6) | i];  // same addr across 16 lanes
    v4f o;
    o.x = fmaxf(xv, k.x);
    o.y = fmaxf(xv, k.y);
    o.z = fmaxf(xv, k.z);
    o.w = fmaxf(xv, k.w);
    __builtin_nontemporal_store(o, &out4[v]);  // streaming global_store_dwordx4 nt
  }
}

extern "C" void kernel_launch(void* const* d_in, const int* in_sizes, int n_in,
                              void* d_out, int out_size, void* d_ws, size_t ws_size,
                              hipStream_t stream) {
  const float* x = reinterpret_cast<const float*>(d_in[0]);   // (8,2048,64) fp32
  const float* km = reinterpret_cast<const float*>(d_in[1]);  // (64,64) fp32
  float* out = reinterpret_cast<float*>(d_out);

  const unsigned total4 = (unsigned)(out_size / 4);  // 16,777,216 float4s
  const int block = 256;
  const int grid = 8192;  // 2M threads, 8 float4/thread; stride = 2^21 (mult of 1024)
  fuzzy_max_kernel<<<grid, block, 0, stream>>>(x, km, out, total4);
}